// Round 15
// baseline (99.442 us; speedup 1.0000x reference)
//
#include <hip/hip_runtime.h>
#include <hip/hip_bf16.h>

typedef __bf16 bf16_t;
typedef __bf16 bf16x8 __attribute__((ext_vector_type(8)));
typedef __bf16 bf16x4 __attribute__((ext_vector_type(4)));
typedef short short4v __attribute__((ext_vector_type(4)));
typedef float f32x4 __attribute__((ext_vector_type(4)));

static_assert(sizeof(bf16x8) == 16, "bf16x8 must be 16B");

// Problem constants
#define BB 2
#define SS 2048
#define DD 512
#define HH 8
#define DH 64
#define LOG2E 1.44269504088896f
// HID == 512; head block = contiguous [2048,64] at (b*8+h)*131072 (flat view).

// ------------- transpose + cast weights: Wt[n][k] = (bf16)W[k][n]  [R1-R7 passed] ---------
__global__ void transpose_w(const float* __restrict__ w0, const float* __restrict__ w1,
                            const float* __restrict__ w2, const float* __restrict__ w3,
                            bf16_t* __restrict__ wt) {
  __shared__ float tile[32][33];
  const float* W = (blockIdx.z == 0) ? w0 : (blockIdx.z == 1) ? w1 : (blockIdx.z == 2) ? w2 : w3;
  bf16_t* out = wt + (size_t)blockIdx.z * 512 * 512;
  int tx = threadIdx.x, ty = threadIdx.y;          // block (32,8)
  int nb = blockIdx.x * 32, kb = blockIdx.y * 32;
#pragma unroll
  for (int i = 0; i < 4; i++)
    tile[ty + i * 8][tx] = W[(size_t)(kb + ty + i * 8) * 512 + nb + tx];
  __syncthreads();
#pragma unroll
  for (int i = 0; i < 4; i++)
    out[(size_t)(nb + ty + i * 8) * 512 + kb + tx] = (bf16_t)tile[tx][ty + i * 8];
}

// ------------- GEMM: C[M,N] = (A @ Bt^T + bias) * (z==0 ? s0 : 1) ----------
// Templated tile: BM x BN, BK=64, 256 thr, 4 waves 2x2. B via global_load_lds(16B).
// AF32=1: A is read as RAW F32 (per-z pointer a0/a1/a2) with T14 load/write-split
// reg-staging (loads issued early, cvt+ds_write after compute) — fuses the
// f32->bf16 cast into the GEMM, eliminating the prep cast pass.
// AF32=0: A is bf16, staged via global_load_lds (R8-proven path).
template <int BM, int BN, int WM, int WN, int AF32, typename OutT>
__global__ __launch_bounds__(256) void gemm2(
    const bf16_t* __restrict__ Abf, const float* __restrict__ a0,
    const float* __restrict__ a1, const float* __restrict__ a2,
    const bf16_t* __restrict__ Btbase,
    const float* __restrict__ bias0, const float* __restrict__ bias1,
    const float* __restrict__ bias2, OutT* __restrict__ Cbase,
    int M, int N, int K, long Bz, long Cz, float scale0) {
  static_assert(BM == 2 * WM && BN == 2 * WN, "2x2 wave grid");
  constexpr int FM = WM / 16, FN = WN / 16;
  constexpr int AJ = BM / 32, BJ = BN / 32;

  const float* Af = (blockIdx.z == 0) ? a0 : (blockIdx.z == 1) ? a1 : a2;
  const bf16_t* Bt = Btbase + (size_t)blockIdx.z * Bz;
  const float* bias = (blockIdx.z == 0) ? bias0 : (blockIdx.z == 1) ? bias1 : bias2;
  OutT* C = Cbase + (size_t)blockIdx.z * Cz;
  const float osc = (blockIdx.z == 0) ? scale0 : 1.0f;

  __shared__ bf16_t As[2][BM * 64];
  __shared__ bf16_t Bs[2][BN * 64];

  const int tid = threadIdx.x, w = tid >> 6, l = tid & 63;
  const int bm = blockIdx.y, bn = blockIdx.x;
  const int wm0 = (w >> 1) * WM, wn0 = (w & 1) * WN;
  const int lr = l & 15, lg = l >> 4;

  f32x4 acc[FM][FN] = {};
  float4 areg[AF32 ? 2 * AJ : 1][AF32 ? 1 : 1];   // f32 A staging regs (AF32 path)
  float4 ar[2 * (AF32 ? AJ : 1)];

  // --- staging helpers ---
  auto load_a = [&](int kt) {                      // AF32: issue f32 loads early
    if constexpr (AF32) {
#pragma unroll
      for (int j = 0; j < AJ; j++) {
        int lin = j * 256 + tid;                   // 8-elem chunk index
        int row = lin >> 3, cc = lin & 7;
        const float* g = Af + (size_t)(bm * BM + row) * K + kt * 64 + cc * 8;
        ar[j * 2 + 0] = *(const float4*)(g);
        ar[j * 2 + 1] = *(const float4*)(g + 4);
      }
    }
  };
  auto write_a = [&](int buf) {                    // AF32: cvt + ds_write after compute
    if constexpr (AF32) {
#pragma unroll
      for (int j = 0; j < AJ; j++) {
        int lin = j * 256 + tid;
        bf16x8 o;
        o[0] = (bf16_t)ar[j * 2 + 0].x; o[1] = (bf16_t)ar[j * 2 + 0].y;
        o[2] = (bf16_t)ar[j * 2 + 0].z; o[3] = (bf16_t)ar[j * 2 + 0].w;
        o[4] = (bf16_t)ar[j * 2 + 1].x; o[5] = (bf16_t)ar[j * 2 + 1].y;
        o[6] = (bf16_t)ar[j * 2 + 1].z; o[7] = (bf16_t)ar[j * 2 + 1].w;
        *(bf16x8*)(&As[buf][lin * 8]) = o;
      }
    }
  };
  auto stage_a_bf = [&](int buf, int kt) {         // AF32==0: gload_lds path
    if constexpr (!AF32) {
#pragma unroll
      for (int j = 0; j < AJ; j++) {
        int lin = j * 256 + tid;
        int row = lin >> 3, cc = lin & 7;
        const bf16_t* g = Abf + (size_t)(bm * BM + row) * K + kt * 64 + cc * 8;
        __builtin_amdgcn_global_load_lds(
            (const __attribute__((address_space(1))) void*)g,
            (__attribute__((address_space(3))) void*)(&As[buf][(j * 256 + w * 64) * 8]), 16, 0, 0);
      }
    }
  };
  auto stage_b = [&](int buf, int kt) {
#pragma unroll
    for (int j = 0; j < BJ; j++) {
      int lin = j * 256 + tid;
      int row = lin >> 3, cc = lin & 7;
      const bf16_t* g = Bt + (size_t)(bn * BN + row) * K + kt * 64 + cc * 8;
      __builtin_amdgcn_global_load_lds(
          (const __attribute__((address_space(1))) void*)g,
          (__attribute__((address_space(3))) void*)(&Bs[buf][(j * 256 + w * 64) * 8]), 16, 0, 0);
    }
  };

  // prologue: stage tile 0
  load_a(0);
  stage_b(0, 0);
  stage_a_bf(0, 0);
  write_a(0);

  const int KT = K >> 6;
  for (int kt = 0; kt < KT; kt++) {
    __syncthreads();                         // tile kt ready (vmcnt+lgkmcnt drained)
    if (kt + 1 < KT) {
      load_a(kt + 1);                        // f32 loads in flight during compute
      stage_b((kt + 1) & 1, kt + 1);
      stage_a_bf((kt + 1) & 1, kt + 1);
    }
    const bf16_t* as = As[kt & 1];
    const bf16_t* bs = Bs[kt & 1];
#pragma unroll
    for (int kc = 0; kc < 2; kc++) {
      bf16x8 a[FM], b[FN];
#pragma unroll
      for (int i = 0; i < FM; i++)
        a[i] = *(const bf16x8*)(as + (wm0 + i * 16 + lr) * 64 + kc * 32 + lg * 8);
#pragma unroll
      for (int j = 0; j < FN; j++)
        b[j] = *(const bf16x8*)(bs + (wn0 + j * 16 + lr) * 64 + kc * 32 + lg * 8);
#pragma unroll
      for (int i = 0; i < FM; i++)
#pragma unroll
        for (int j = 0; j < FN; j++)
          acc[i][j] = __builtin_amdgcn_mfma_f32_16x16x32_bf16(a[i], b[j], acc[i][j], 0, 0, 0);
    }
    if (kt + 1 < KT) write_a((kt + 1) & 1);  // cvt+ds_write into other buffer
  }

  // epilogue: C row = (lane>>4)*4+reg, col = lane&15 (verified m89/m91 layout)
  const int row0 = bm * BM + wm0, col0 = bn * BN + wn0;
#pragma unroll
  for (int j = 0; j < FN; j++) {
    int col = col0 + j * 16 + lr;
    float bv = bias[col];
#pragma unroll
    for (int i = 0; i < FM; i++) {
      int row = row0 + i * 16 + lg * 4;
#pragma unroll
      for (int r = 0; r < 4; r++) {
        float vv = (acc[i][j][r] + bv) * osc;
        C[(size_t)(row + r) * N + col] = (OutT)vv;
      }
    }
  }
}

// ------------- flash attention, KV-split x4, KVBLK=32, 16KB LDS  [R14-passed verbatim] -----
__global__ __launch_bounds__(256, 8) void attn_flash(const bf16_t* __restrict__ qp,
                                                     const bf16_t* __restrict__ kp,
                                                     const bf16_t* __restrict__ vp,
                                                     bf16_t* __restrict__ Opart,
                                                     float* __restrict__ mlpart) {
  const int id = blockIdx.x;
  const int bh = (id & 7) | (((id >> 3) & 1) << 3);
  const int qt = (id >> 4) & 31;
  const int quarter = id >> 9;                    // 0..3
  const int pidx = (((qt << 4) | bh) << 2) + quarter;

  const int tid = threadIdx.x, w = tid >> 6, l = tid & 63;
  const int lr = l & 15, lg = l >> 4;
  const size_t hb = (size_t)bh * (SS * DH);
  const bf16_t* Q = qp + hb;
  const bf16_t* Kh = kp + hb;
  const bf16_t* Vh = vp + hb;

  __shared__ __align__(16) bf16_t KsL[2][2048];   // 2 x 4KB  [32 kv][64 d] swizzled
  __shared__ __align__(16) bf16_t VtL[2][2048];   // 2 x 4KB  [64 d][32 kv] swizzled

  const int qr0 = qt * 64 + w * 16;

  bf16x8 aq[2];
#pragma unroll
  for (int kc = 0; kc < 2; kc++)
    aq[kc] = *(const bf16x8*)(Q + (size_t)(qr0 + lr) * DH + kc * 32 + lg * 8);

  f32x4 o[4] = {};                    // O^T[d = n*16+lg*4+r][q = lr]
  float m_run = -1e30f, l_run = 0.f;  // log2-domain m; per-lane partial l

  const int krow = (w << 3) + (l >> 3);
  const int kcol = ((l & 7) ^ (l >> 3)) << 3;     // element offset
  const bf16_t* ks_it = Kh + (size_t)(quarter * 16) * 2048 + krow * 64 + kcol;

  auto stage_k = [&](int buf, const bf16_t* ks) {
    char* kb = (char*)&KsL[buf][0];
    __builtin_amdgcn_global_load_lds((const __attribute__((address_space(1))) void*)ks,
        (__attribute__((address_space(3))) void*)(kb + (w << 10)), 16, 0, 0);
  };

  const int vkv = l & 31;
  const int vdv = (w << 1) | (l >> 5);
  bf16x8 vreg;
  auto load_v = [&](int it) {
    vreg = *(const bf16x8*)(Vh + ((size_t)it * 32 + vkv) * DH + vdv * 8);
  };
  auto write_v = [&](int buf) {
    char* vt = (char*)&VtL[buf][0];
#pragma unroll
    for (int j = 0; j < 8; j++) {
      int d = vdv * 8 + j;                        // d&7 == j
      *(bf16_t*)(vt + d * 64 + ((vkv << 1) ^ (j << 3))) = vreg[j];
    }
  };

  const int it0 = quarter * 16;
  stage_k(0, ks_it);
  load_v(it0);
  write_v(0);

  for (int i = 0; i < 16; i++) {
    const int buf = i & 1;
    __syncthreads();
    if (i + 1 < 16) {
      ks_it += 2048;
      stage_k(buf ^ 1, ks_it);
      load_v(it0 + i + 1);
    }

    const char* ksb = (const char*)&KsL[buf][0];
    f32x4 s[2] = {};
    __builtin_amdgcn_s_setprio(1);
#pragma unroll
    for (int kc = 0; kc < 2; kc++) {
#pragma unroll
      for (int n = 0; n < 2; n++) {
        bf16x8 bk = *(const bf16x8*)(ksb + (n * 16 + lr) * 128 +
                                     ((kc * 64 + lg * 16) ^ ((lr & 7) << 4)));
        s[n] = __builtin_amdgcn_mfma_f32_16x16x32_bf16(bk, aq[kc], s[n], 0, 0, 0);
      }
    }
    __builtin_amdgcn_s_setprio(0);

    float pmax = -1e30f;
#pragma unroll
    for (int n = 0; n < 2; n++)
#pragma unroll
      for (int r = 0; r < 4; r++) pmax = fmaxf(pmax, s[n][r]);
    pmax = fmaxf(pmax, __shfl_xor(pmax, 16));
    pmax = fmaxf(pmax, __shfl_xor(pmax, 32));
    if (!__all(pmax <= m_run + 8.0f)) {
      float mnew = fmaxf(m_run, pmax);
      float scale = exp2f(m_run - mnew);
      l_run *= scale;
#pragma unroll
      for (int n = 0; n < 4; n++)
#pragma unroll
        for (int r = 0; r < 4; r++) o[n][r] *= scale;
      m_run = mnew;
    }
    float rs = 0.f;
#pragma unroll
    for (int n = 0; n < 2; n++)
#pragma unroll
      for (int r = 0; r < 4; r++) {
        float e = exp2f(s[n][r] - m_run);
        s[n][r] = e;
        rs += e;
      }
    l_run += rs;

    short4v pb[2];
#pragma unroll
    for (int c2 = 0; c2 < 2; c2++) {
      bf16x4 t;
#pragma unroll
      for (int r = 0; r < 4; r++) t[r] = (bf16_t)s[c2][r];
      pb[c2] = __builtin_bit_cast(short4v, t);
    }
    const char* vtb = (const char*)&VtL[buf][0];
    __builtin_amdgcn_s_setprio(1);
#pragma unroll
    for (int nd = 0; nd < 4; nd++) {
#pragma unroll
      for (int c2 = 0; c2 < 2; c2++) {
        bf16x4 bvh = *(const bf16x4*)(vtb + (nd * 16 + lr) * 64 +
                                      ((c2 * 32 + lg * 8) ^ ((lr & 7) << 3)));
        o[nd] = __builtin_amdgcn_mfma_f32_16x16x16bf16_1k(
            __builtin_bit_cast(short4v, bvh), pb[c2], o[nd], 0, 0, 0);
      }
    }
    __builtin_amdgcn_s_setprio(0);

    if (i + 1 < 16) write_v(buf ^ 1);
  }

  l_run += __shfl_xor(l_run, 16);
  l_run += __shfl_xor(l_run, 32);

  bf16_t* ob = Opart + (size_t)pidx * 4096;
#pragma unroll
  for (int n = 0; n < 4; n++) {
    bf16x4 t;
#pragma unroll
    for (int r = 0; r < 4; r++) t[r] = (bf16_t)o[n][r];
    *(bf16x4*)(ob + ((w * 4 + n) * 64 + l) * 4) = t;
  }
  if (lg == 0) {
    mlpart[(size_t)pidx * 128 + (w * 16 + lr) * 2 + 0] = m_run;
    mlpart[(size_t)pidx * 128 + (w * 16 + lr) * 2 + 1] = l_run;
  }
}

// ------------- combine the four KV-quarters -> ctx (bf16)  [R14-passed verbatim] ---------
__global__ __launch_bounds__(256) void attn_combine(const bf16_t* __restrict__ Opart,
                                                    const float* __restrict__ mlpart,
                                                    bf16_t* __restrict__ ctx) {
  const int gid = blockIdx.x;                // 512 = qt*16 + bh
  const int qt = gid >> 4, bh = gid & 15;
  const int t = threadIdx.x, w = t >> 6, l = t & 63;
  const int lr = l & 15, lg = l >> 4;
  const int q = w * 16 + lr;

  float mv[4], lv[4];
#pragma unroll
  for (int s = 0; s < 4; s++) {
    const float* ml = mlpart + (size_t)(gid * 4 + s) * 128 + q * 2;
    mv[s] = ml[0];
    lv[s] = ml[1];
  }
  float m = fmaxf(fmaxf(mv[0], mv[1]), fmaxf(mv[2], mv[3]));
  float e[4], denom = 0.f;
#pragma unroll
  for (int s = 0; s < 4; s++) { e[s] = exp2f(mv[s] - m); denom += lv[s] * e[s]; }
  denom *= 8.0f;                             // /sqrt(DH) applied after softmax
  float f[4];
#pragma unroll
  for (int s = 0; s < 4; s++) f[s] = e[s] / denom;

  const int b = bh >> 3, h = bh & 7;
  const int trow = qt * 64 + q;
  size_t rowbase = ((size_t)b * SS + trow) * 512 + h * 64;

#pragma unroll
  for (int n = 0; n < 4; n++) {
    float acc[4] = {0.f, 0.f, 0.f, 0.f};
#pragma unroll
    for (int s = 0; s < 4; s++) {
      bf16x4 v = *(const bf16x4*)(Opart + (size_t)(gid * 4 + s) * 4096 +
                                  ((w * 4 + n) * 64 + l) * 4);
#pragma unroll
      for (int r = 0; r < 4; r++) acc[r] += (float)v[r] * f[s];
    }
    bf16x4 ov;
#pragma unroll
    for (int r = 0; r < 4; r++) ov[r] = (bf16_t)acc[r];
    *(bf16x4*)(&ctx[rowbase + n * 16 + lg * 4]) = ov;
  }
}

// ---------------- launcher ----------------
extern "C" void kernel_launch(void* const* d_in, const int* in_sizes, int n_in,
                              void* d_out, int out_size, void* d_ws, size_t ws_size,
                              hipStream_t stream) {
  const float* q  = (const float*)d_in[0];
  const float* k  = (const float*)d_in[1];
  const float* v  = (const float*)d_in[2];
  const float* Wq = (const float*)d_in[3];
  const float* bq = (const float*)d_in[4];
  const float* Wk = (const float*)d_in[5];
  const float* bk = (const float*)d_in[6];
  const float* Wv = (const float*)d_in[7];
  const float* bv = (const float*)d_in[8];
  const float* Wo = (const float*)d_in[9];
  const float* bo = (const float*)d_in[10];

  const size_t NQKV = (size_t)4096 * 512;   // 2,097,152 elems per tensor
  const size_t NW = (size_t)512 * 512;

  // ws layout (bf16 elems): [wt 4NW][proj 3NQKV][ctx NQKV][Opart 16MB][mlpart 1MB]
  bf16_t* ws   = (bf16_t*)d_ws;
  bf16_t* wt   = ws;                 // 2 MB
  bf16_t* proj = wt + 4 * NW;        // 12 MB (qp, kp, vp)
  bf16_t* ctx  = proj + 3 * NQKV;    // 4 MB
  bf16_t* Opart = ctx + NQKV;        // 16 MB  (2048 partials x 4096 bf16)
  float* mlpart = (float*)(Opart + (size_t)2048 * 4096);  // 1 MB

  // 1. transpose+cast weights (tiny)
  transpose_w<<<dim3(16, 16, 4), dim3(32, 8), 0, stream>>>(Wq, Wk, Wv, Wo, wt);
  // 2. fused QKV projections reading RAW F32 q/k/v (cast fused into staging);
  //    Q output pre-scaled by log2e (exp2-domain softmax)
  gemm2<128, 64, 64, 32, 1, bf16_t><<<dim3(8, 32, 3), 256, 0, stream>>>(
      nullptr, q, k, v, wt, bq, bk, bv, proj, 4096, 512, 512, (long)NW, (long)NQKV, LOG2E);
  // 3. flash attention, KV-split x4 (2048 blocks = 8/CU, XCD-affine), 16KB LDS
  attn_flash<<<2048, 256, 0, stream>>>(proj, proj + NQKV, proj + 2 * NQKV, Opart, mlpart);
  // 4. combine quarters -> ctx
  attn_combine<<<512, 256, 0, stream>>>(Opart, mlpart, ctx);
  // 5. output projection (f32 out), A = ctx (bf16, gload_lds path)
  gemm2<64, 64, 32, 32, 0, float><<<dim3(8, 64, 1), 256, 0, stream>>>(
      ctx, nullptr, nullptr, nullptr, wt + 3 * NW, bo, bo, bo, (float*)d_out,
      4096, 512, 512, 0, 0, 1.0f);
}

// Round 16
// 92.016 us; speedup vs baseline: 1.0807x; 1.0807x over previous
//
#include <hip/hip_runtime.h>
#include <hip/hip_bf16.h>

typedef __bf16 bf16_t;
typedef __bf16 bf16x8 __attribute__((ext_vector_type(8)));
typedef __bf16 bf16x4 __attribute__((ext_vector_type(4)));
typedef short short4v __attribute__((ext_vector_type(4)));
typedef float f32x4 __attribute__((ext_vector_type(4)));

static_assert(sizeof(bf16x8) == 16, "bf16x8 must be 16B");

// Problem constants
#define BB 2
#define SS 2048
#define DD 512
#define HH 8
#define DH 64
#define LOG2E 1.44269504088896f
// HID == 512; head block = contiguous [2048,64] at (b*8+h)*131072 (flat view).

// ------------- prep: z=0..2 cast q/k/v f32->bf16; z=3 transpose+cast weights -------------
__global__ void prep(const float* __restrict__ q, const float* __restrict__ k,
                     const float* __restrict__ v, const float* __restrict__ w0,
                     const float* __restrict__ w1, const float* __restrict__ w2,
                     const float* __restrict__ w3, bf16_t* __restrict__ qkvb,
                     bf16_t* __restrict__ wt, int n) {
  const int tid = threadIdx.x;
  if (blockIdx.z < 3) {
    const float* src = (blockIdx.z == 0) ? q : (blockIdx.z == 1) ? k : v;
    bf16_t* out = qkvb + (size_t)blockIdx.z * n;
    int i = (blockIdx.x * 256 + tid) * 8;
    if (i >= n) return;
    const float4* s4 = (const float4*)(src + i);
    float4 a = s4[0], b = s4[1];
    bf16x8 o;
    o[0] = (bf16_t)a.x; o[1] = (bf16_t)a.y; o[2] = (bf16_t)a.z; o[3] = (bf16_t)a.w;
    o[4] = (bf16_t)b.x; o[5] = (bf16_t)b.y; o[6] = (bf16_t)b.z; o[7] = (bf16_t)b.w;
    *(bf16x8*)(out + i) = o;
  } else {
    // transpose+cast: Wt[nn][kk] = (bf16)W[kk][nn]
    __shared__ float tile[32][33];
    const int x = blockIdx.x;                  // 0..1023
    const int wsel = x >> 8;
    const int nb = ((x >> 4) & 15) * 32, kb = (x & 15) * 32;
    const int tx = tid & 31, ty = tid >> 5;    // (32,8)
    const float* W = (wsel == 0) ? w0 : (wsel == 1) ? w1 : (wsel == 2) ? w2 : w3;
    bf16_t* out = wt + (size_t)wsel * 512 * 512;
#pragma unroll
    for (int i = 0; i < 4; i++)
      tile[ty + i * 8][tx] = W[(size_t)(kb + ty + i * 8) * 512 + nb + tx];
    __syncthreads();
#pragma unroll
    for (int i = 0; i < 4; i++)
      out[(size_t)(nb + ty + i * 8) * 512 + kb + tx] = (bf16_t)tile[tx][ty + i * 8];
  }
}

// ------------- GEMM: C[M,N] = (A[M,K] @ Bt[N,K]^T + bias[N]) * (z==0 ? s0 : 1) ----------
// Templated tile: BM x BN, BK=64, 256 thr, 4 waves 2x2. global_load_lds(16B), dbuf LDS.
// [R8/R14-proven structure]
template <int BM, int BN, int WM, int WN, typename OutT>
__global__ __launch_bounds__(256) void gemm2(
    const bf16_t* __restrict__ Abase, const bf16_t* __restrict__ Btbase,
    const float* __restrict__ bias0, const float* __restrict__ bias1,
    const float* __restrict__ bias2, OutT* __restrict__ Cbase,
    int M, int N, int K, long Az, long Bz, long Cz, float scale0) {
  static_assert(BM == 2 * WM && BN == 2 * WN, "2x2 wave grid");
  constexpr int FM = WM / 16, FN = WN / 16;
  constexpr int AJ = BM / 32, BJ = BN / 32;

  const bf16_t* A  = Abase + (size_t)blockIdx.z * Az;
  const bf16_t* Bt = Btbase + (size_t)blockIdx.z * Bz;
  const float* bias = (blockIdx.z == 0) ? bias0 : (blockIdx.z == 1) ? bias1 : bias2;
  OutT* C = Cbase + (size_t)blockIdx.z * Cz;
  const float osc = (blockIdx.z == 0) ? scale0 : 1.0f;

  __shared__ bf16_t As[2][BM * 64];
  __shared__ bf16_t Bs[2][BN * 64];

  const int tid = threadIdx.x, w = tid >> 6, l = tid & 63;
  const int bm = blockIdx.y, bn = blockIdx.x;
  const int wm0 = (w >> 1) * WM, wn0 = (w & 1) * WN;
  const int lr = l & 15, lg = l >> 4;

  f32x4 acc[FM][FN] = {};

  auto stage = [&](int buf, int kt) {
#pragma unroll
    for (int j = 0; j < AJ; j++) {
      int lin = j * 256 + tid;              // 16B-chunk index
      int row = lin >> 3, cc = lin & 7;
      const bf16_t* g = A + (size_t)(bm * BM + row) * K + kt * 64 + cc * 8;
      __builtin_amdgcn_global_load_lds(
          (const __attribute__((address_space(1))) void*)g,
          (__attribute__((address_space(3))) void*)(&As[buf][(j * 256 + w * 64) * 8]), 16, 0, 0);
    }
#pragma unroll
    for (int j = 0; j < BJ; j++) {
      int lin = j * 256 + tid;
      int row = lin >> 3, cc = lin & 7;
      const bf16_t* g = Bt + (size_t)(bn * BN + row) * K + kt * 64 + cc * 8;
      __builtin_amdgcn_global_load_lds(
          (const __attribute__((address_space(1))) void*)g,
          (__attribute__((address_space(3))) void*)(&Bs[buf][(j * 256 + w * 64) * 8]), 16, 0, 0);
    }
  };

  stage(0, 0);
  const int KT = K >> 6;
  for (int kt = 0; kt < KT; kt++) {
    __syncthreads();                         // drains vmcnt -> buf[kt&1] ready
    if (kt + 1 < KT) stage((kt + 1) & 1, kt + 1);
    const bf16_t* as = As[kt & 1];
    const bf16_t* bs = Bs[kt & 1];
#pragma unroll
    for (int kc = 0; kc < 2; kc++) {
      bf16x8 a[FM], b[FN];
#pragma unroll
      for (int i = 0; i < FM; i++)
        a[i] = *(const bf16x8*)(as + (wm0 + i * 16 + lr) * 64 + kc * 32 + lg * 8);
#pragma unroll
      for (int j = 0; j < FN; j++)
        b[j] = *(const bf16x8*)(bs + (wn0 + j * 16 + lr) * 64 + kc * 32 + lg * 8);
#pragma unroll
      for (int i = 0; i < FM; i++)
#pragma unroll
        for (int j = 0; j < FN; j++)
          acc[i][j] = __builtin_amdgcn_mfma_f32_16x16x32_bf16(a[i], b[j], acc[i][j], 0, 0, 0);
    }
  }

  // epilogue: C row = (lane>>4)*4+reg, col = lane&15 (verified m89/m91 layout)
  const int row0 = bm * BM + wm0, col0 = bn * BN + wn0;
#pragma unroll
  for (int j = 0; j < FN; j++) {
    int col = col0 + j * 16 + lr;
    float bv = bias[col];
#pragma unroll
    for (int i = 0; i < FM; i++) {
      int row = row0 + i * 16 + lg * 4;
#pragma unroll
      for (int r = 0; r < 4; r++) {
        float vv = (acc[i][j][r] + bv) * osc;
        C[(size_t)(row + r) * N + col] = (OutT)vv;
      }
    }
  }
}

// ------------- flash attention, KV-split x4, KVBLK=32, 2 TILES PER BARRIER ---------
// grid 2048: id -> bh low3 (XCD-affinity), bh hi, qt, quarter. 4 waves, QBLK=64.
// Single-variable change vs R14 (passed, 49.1us): K and V LDS go 4-deep
// (tile t -> buffer t&3, 32KB total, 4 blocks/CU = R8-proven occupancy point)
// and each loop body processes 2 KV-tiles under ONE __syncthreads -> barriers
// per block 16 -> 8. Per-tile compute/softmax/PV code byte-identical to R14;
// buffer-lifetime: end-of-body writes target the pair consumed in body i-1,
// whose readers all passed this body's top barrier.
__global__ __launch_bounds__(256, 4) void attn_flash(const bf16_t* __restrict__ qp,
                                                     const bf16_t* __restrict__ kp,
                                                     const bf16_t* __restrict__ vp,
                                                     bf16_t* __restrict__ Opart,
                                                     float* __restrict__ mlpart) {
  const int id = blockIdx.x;
  const int bh = (id & 7) | (((id >> 3) & 1) << 3);
  const int qt = (id >> 4) & 31;
  const int quarter = id >> 9;                    // 0..3
  const int pidx = (((qt << 4) | bh) << 2) + quarter;

  const int tid = threadIdx.x, w = tid >> 6, l = tid & 63;
  const int lr = l & 15, lg = l >> 4;
  const size_t hb = (size_t)bh * (SS * DH);
  const bf16_t* Q = qp + hb;
  const bf16_t* Kh = kp + hb;
  const bf16_t* Vh = vp + hb;

  __shared__ __align__(16) bf16_t KsL[4][2048];   // 4 x 4KB  [32 kv][64 d] swizzled
  __shared__ __align__(16) bf16_t VtL[4][2048];   // 4 x 4KB  [64 d][32 kv] swizzled

  const int qr0 = qt * 64 + w * 16;

  bf16x8 aq[2];
#pragma unroll
  for (int kc = 0; kc < 2; kc++)
    aq[kc] = *(const bf16x8*)(Q + (size_t)(qr0 + lr) * DH + kc * 32 + lg * 8);

  f32x4 o[4] = {};                    // O^T[d = n*16+lg*4+r][q = lr]
  float m_run = -1e30f, l_run = 0.f;  // log2-domain m; per-lane partial l

  // K staging: chunk c = tid -> row c>>3 (0..31), slot (c&7)*16B, pre-swizzled src
  const int krow = (w << 3) + (l >> 3);
  const int kcol = ((l & 7) ^ (l >> 3)) << 3;     // element offset
  const bf16_t* ks_it = Kh + (size_t)(quarter * 16) * 2048 + krow * 64 + kcol;

  auto stage_k = [&](int buf, const bf16_t* ks) {
    char* kb = (char*)&KsL[buf][0];
    __builtin_amdgcn_global_load_lds((const __attribute__((address_space(1))) void*)ks,
        (__attribute__((address_space(3))) void*)(kb + (w << 10)), 16, 0, 0);
  };

  // V staging (reg roundtrip, R14-proven): kv = l&31, dv = (w<<1)|(l>>5)
  const int vkv = l & 31;
  const int vdv = (w << 1) | (l >> 5);
  bf16x8 vregA, vregB;
  auto load_vA = [&](int it) {
    vregA = *(const bf16x8*)(Vh + ((size_t)it * 32 + vkv) * DH + vdv * 8);
  };
  auto load_vB = [&](int it) {
    vregB = *(const bf16x8*)(Vh + ((size_t)it * 32 + vkv) * DH + vdv * 8);
  };
  auto write_vA = [&](int buf) {
    char* vt = (char*)&VtL[buf][0];
#pragma unroll
    for (int j = 0; j < 8; j++) {
      int d = vdv * 8 + j;                        // d&7 == j
      *(bf16_t*)(vt + d * 64 + ((vkv << 1) ^ (j << 3))) = vregA[j];
    }
  };
  auto write_vB = [&](int buf) {
    char* vt = (char*)&VtL[buf][0];
#pragma unroll
    for (int j = 0; j < 8; j++) {
      int d = vdv * 8 + j;
      *(bf16_t*)(vt + d * 64 + ((vkv << 1) ^ (j << 3))) = vregB[j];
    }
  };

  // per-tile compute (byte-identical math to R14)
  auto tile_body = [&](int buf) {
    const char* ksb = (const char*)&KsL[buf][0];
    f32x4 s[2] = {};
    __builtin_amdgcn_s_setprio(1);
#pragma unroll
    for (int kc = 0; kc < 2; kc++) {
#pragma unroll
      for (int n = 0; n < 2; n++) {
        bf16x8 bk = *(const bf16x8*)(ksb + (n * 16 + lr) * 128 +
                                     ((kc * 64 + lg * 16) ^ ((lr & 7) << 4)));
        s[n] = __builtin_amdgcn_mfma_f32_16x16x32_bf16(bk, aq[kc], s[n], 0, 0, 0);
      }
    }
    __builtin_amdgcn_s_setprio(0);

    float pmax = -1e30f;
#pragma unroll
    for (int n = 0; n < 2; n++)
#pragma unroll
      for (int r = 0; r < 4; r++) pmax = fmaxf(pmax, s[n][r]);
    pmax = fmaxf(pmax, __shfl_xor(pmax, 16));
    pmax = fmaxf(pmax, __shfl_xor(pmax, 32));
    if (!__all(pmax <= m_run + 8.0f)) {
      float mnew = fmaxf(m_run, pmax);
      float scale = exp2f(m_run - mnew);   // per-lane uniform (O^T layout)
      l_run *= scale;
#pragma unroll
      for (int n = 0; n < 4; n++)
#pragma unroll
        for (int r = 0; r < 4; r++) o[n][r] *= scale;
      m_run = mnew;
    }
    float rs = 0.f;
#pragma unroll
    for (int n = 0; n < 2; n++)
#pragma unroll
      for (int r = 0; r < 4; r++) {
        float e = exp2f(s[n][r] - m_run);
        s[n][r] = e;
        rs += e;
      }
    l_run += rs;                          // cross-lane sum deferred to end

    short4v pb[2];
#pragma unroll
    for (int c2 = 0; c2 < 2; c2++) {
      bf16x4 t;
#pragma unroll
      for (int r = 0; r < 4; r++) t[r] = (bf16_t)s[c2][r];
      pb[c2] = __builtin_bit_cast(short4v, t);
    }
    const char* vtb = (const char*)&VtL[buf][0];
    __builtin_amdgcn_s_setprio(1);
#pragma unroll
    for (int nd = 0; nd < 4; nd++) {
#pragma unroll
      for (int c2 = 0; c2 < 2; c2++) {
        bf16x4 bvh = *(const bf16x4*)(vtb + (nd * 16 + lr) * 64 +
                                      ((c2 * 32 + lg * 8) ^ ((lr & 7) << 3)));
        o[nd] = __builtin_amdgcn_mfma_f32_16x16x16bf16_1k(
            __builtin_bit_cast(short4v, bvh), pb[c2], o[nd], 0, 0, 0);
      }
    }
    __builtin_amdgcn_s_setprio(0);
  };

  const int it0 = quarter * 16;
  // prologue: stage pair 0 (tiles 0,1 -> buffers 0,1)
  stage_k(0, ks_it);
  stage_k(1, ks_it + 2048);
  load_vA(it0);
  load_vB(it0 + 1);
  write_vA(0);
  write_vB(1);

  for (int i = 0; i < 8; i++) {
    const int ta = 2 * i;
    __syncthreads();                 // pair i K-gloads drained + V writes visible
    if (i + 1 < 8) {
      ks_it += 4096;
      stage_k((ta + 2) & 3, ks_it);
      stage_k((ta + 3) & 3, ks_it + 2048);
      load_vA(it0 + ta + 2);
      load_vB(it0 + ta + 3);
    }

    tile_body(ta & 3);               // tile 2i
    tile_body((ta + 1) & 3);         // tile 2i+1

    // write next pair's V into buffers of pair i-1 (readers passed top barrier)
    if (i + 1 < 8) {
      write_vA((ta + 2) & 3);
      write_vB((ta + 3) & 3);
    }
  }

  // final cross-lane l reduction (deferred)
  l_run += __shfl_xor(l_run, 16);
  l_run += __shfl_xor(l_run, 32);

  // --- write partials: O^T lane-order (coalesced) as bf16; m (log2) / l per q-row ---
  bf16_t* ob = Opart + (size_t)pidx * 4096;
#pragma unroll
  for (int n = 0; n < 4; n++) {
    bf16x4 t;
#pragma unroll
    for (int r = 0; r < 4; r++) t[r] = (bf16_t)o[n][r];
    *(bf16x4*)(ob + ((w * 4 + n) * 64 + l) * 4) = t;
  }
  if (lg == 0) {
    mlpart[(size_t)pidx * 128 + (w * 16 + lr) * 2 + 0] = m_run;
    mlpart[(size_t)pidx * 128 + (w * 16 + lr) * 2 + 1] = l_run;
  }
}

// ------------- combine the four KV-quarters -> ctx (bf16)  [R14-passed verbatim] ---------
__global__ __launch_bounds__(256) void attn_combine(const bf16_t* __restrict__ Opart,
                                                    const float* __restrict__ mlpart,
                                                    bf16_t* __restrict__ ctx) {
  const int gid = blockIdx.x;                // 512 = qt*16 + bh
  const int qt = gid >> 4, bh = gid & 15;
  const int t = threadIdx.x, w = t >> 6, l = t & 63;
  const int lr = l & 15, lg = l >> 4;
  const int q = w * 16 + lr;

  float mv[4], lv[4];
#pragma unroll
  for (int s = 0; s < 4; s++) {
    const float* ml = mlpart + (size_t)(gid * 4 + s) * 128 + q * 2;
    mv[s] = ml[0];
    lv[s] = ml[1];
  }
  float m = fmaxf(fmaxf(mv[0], mv[1]), fmaxf(mv[2], mv[3]));
  float e[4], denom = 0.f;
#pragma unroll
  for (int s = 0; s < 4; s++) { e[s] = exp2f(mv[s] - m); denom += lv[s] * e[s]; }
  denom *= 8.0f;                             // /sqrt(DH) applied after softmax
  float f[4];
#pragma unroll
  for (int s = 0; s < 4; s++) f[s] = e[s] / denom;

  const int b = bh >> 3, h = bh & 7;
  const int trow = qt * 64 + q;
  size_t rowbase = ((size_t)b * SS + trow) * 512 + h * 64;

#pragma unroll
  for (int n = 0; n < 4; n++) {
    float acc[4] = {0.f, 0.f, 0.f, 0.f};
#pragma unroll
    for (int s = 0; s < 4; s++) {
      bf16x4 v = *(const bf16x4*)(Opart + (size_t)(gid * 4 + s) * 4096 +
                                  ((w * 4 + n) * 64 + l) * 4);
#pragma unroll
      for (int r = 0; r < 4; r++) acc[r] += (float)v[r] * f[s];
    }
    bf16x4 ov;
#pragma unroll
    for (int r = 0; r < 4; r++) ov[r] = (bf16_t)acc[r];
    *(bf16x4*)(&ctx[rowbase + n * 16 + lg * 4]) = ov;
  }
}

// ---------------- launcher ----------------
extern "C" void kernel_launch(void* const* d_in, const int* in_sizes, int n_in,
                              void* d_out, int out_size, void* d_ws, size_t ws_size,
                              hipStream_t stream) {
  const float* q  = (const float*)d_in[0];
  const float* k  = (const float*)d_in[1];
  const float* v  = (const float*)d_in[2];
  const float* Wq = (const float*)d_in[3];
  const float* bq = (const float*)d_in[4];
  const float* Wk = (const float*)d_in[5];
  const float* bk = (const float*)d_in[6];
  const float* Wv = (const float*)d_in[7];
  const float* bv = (const float*)d_in[8];
  const float* Wo = (const float*)d_in[9];
  const float* bo = (const float*)d_in[10];

  const size_t NQKV = (size_t)4096 * 512;   // 2,097,152 elems per tensor
  const size_t NW = (size_t)512 * 512;

  // ws layout (bf16 elems): [wt 4NW][proj 3NQKV][ctx NQKV][qkvb 3NQKV ...]
  // Opart (bf16, 16MB) + mlpart (1MB) overlap qkvb (dead after the QKV GEMM).
  bf16_t* ws   = (bf16_t*)d_ws;
  bf16_t* wt   = ws;                 // 2 MB
  bf16_t* proj = wt + 4 * NW;        // 12 MB (qp, kp, vp)
  bf16_t* ctx  = proj + 3 * NQKV;    // 4 MB
  bf16_t* qkvb = ctx + NQKV;         // 12 MB (dead after QKV GEMM)
  bf16_t* Opart = qkvb;              // 16 MB  (2048 partials x 4096 bf16)
  float* mlpart = (float*)(Opart + (size_t)2048 * 4096);  // 1 MB

  // 1. cast q,k,v -> bf16 (z=0..2) + transpose+cast weights (z=3)
  prep<<<dim3(1024, 1, 4), 256, 0, stream>>>(q, k, v, Wq, Wk, Wv, Wo, qkvb, wt, (int)NQKV);
  // 2. fused QKV projections; Q pre-scaled by log2e (exp2-domain softmax)
  gemm2<128, 64, 64, 32, bf16_t><<<dim3(8, 32, 3), 256, 0, stream>>>(
      qkvb, wt, bq, bk, bv, proj, 4096, 512, 512, (long)NQKV, (long)NW, (long)NQKV, LOG2E);
  // 3. flash attention, KV-split x4 (2048 blocks, XCD-affine), 2 tiles/barrier
  attn_flash<<<2048, 256, 0, stream>>>(proj, proj + NQKV, proj + 2 * NQKV, Opart, mlpart);
  // 4. combine quarters -> ctx
  attn_combine<<<512, 256, 0, stream>>>(Opart, mlpart, ctx);
  // 5. output projection (f32 out)
  gemm2<64, 64, 32, 32, float><<<dim3(8, 64, 1), 256, 0, stream>>>(
      ctx, wt + 3 * NW, bo, bo, bo, (float*)d_out, 4096, 512, 512, 0, 0, 0, 1.0f);
}